// Round 4
// baseline (388.434 us; speedup 1.0000x reference)
//
#include <hip/hip_runtime.h>

#define NEG 0.2f

__device__ __forceinline__ float lrelu(float v) { return v > 0.f ? v : NEG * v; }

__device__ __forceinline__ unsigned short f2bf(float f) {
    unsigned u = __float_as_uint(f);
    unsigned r = (u + 0x7FFF + ((u >> 16) & 1)) >> 16;   // RNE
    return (unsigned short)r;
}
__device__ __forceinline__ float bf_lo(unsigned v) { return __uint_as_float(v << 16); }
__device__ __forceinline__ float bf_hi(unsigned v) { return __uint_as_float(v & 0xffff0000u); }

// W1ext[128][80]: cols 0..63 = W1; col 64+j = W1[:, h*32:+32] @ att (j:0=src_h0,1=src_h1,2=dst_h0,3=dst_h1); 68..79 = 0
__global__ void build_w1ext(const float* __restrict__ W1, const float* __restrict__ asrc,
                            const float* __restrict__ adst, float* __restrict__ Wext) {
    int i = blockIdx.x * blockDim.x + threadIdx.x;
    if (i >= 128 * 80) return;
    int k = i / 80, c = i % 80;
    if (c < 64) { Wext[i] = W1[k * 64 + c]; return; }
    if (c >= 68) { Wext[i] = 0.f; return; }
    int j = c - 64;
    int hh = j & 1;
    const float* att = (j >= 2) ? adst : asrc;
    float s = 0.f;
    for (int d = 0; d < 32; ++d) s += W1[k * 64 + hh * 32 + d] * att[hh * 32 + d];
    Wext[i] = s;
}

// W2ext[64][36]: 0..15 = W_mu, 16..31 = W_ls, 32..35 = attention projection vectors
__global__ void build_w2ext(const float* __restrict__ Wmu, const float* __restrict__ Wls,
                            const float* __restrict__ asmu, const float* __restrict__ admu,
                            const float* __restrict__ asls, const float* __restrict__ adls,
                            float* __restrict__ Wext) {
    int i = blockIdx.x * blockDim.x + threadIdx.x;
    if (i >= 64 * 36) return;
    int k = i / 36, c = i % 36;
    if (c < 16) { Wext[i] = Wmu[k * 16 + c]; return; }
    if (c < 32) { Wext[i] = Wls[k * 16 + (c - 16)]; return; }
    int j = c - 32;
    const float* W = (j < 2) ? Wmu : Wls;
    const float* att = (j == 0) ? asmu : (j == 1) ? admu : (j == 2) ? asls : adls;
    float s = 0.f;
    for (int c2 = 0; c2 < 16; ++c2) s += W[k * 16 + c2] * att[c2];
    Wext[i] = s;
}

// h32[N][32] = packed bf16x2 of x @ W1, a1[N][4] f32. 64 rows/block, 4x4 register tile, float4 LDS reads.
__global__ __launch_bounds__(320) void gemm1(const float* __restrict__ x,
                                             const float* __restrict__ Wext,
                                             unsigned* __restrict__ h32, float* __restrict__ a1, int n) {
    __shared__ float xs[64][132];
    __shared__ float Ws[128][80];
    int t = threadIdx.x;
    int row0 = blockIdx.x * 64;
    for (int i = t; i < 128 * 20; i += 320) {
        int r = i / 20, cq = i % 20;
        *(float4*)&Ws[r][cq * 4] = *(const float4*)&Wext[r * 80 + cq * 4];
    }
    for (int i = t; i < 64 * 32; i += 320) {
        int r = i >> 5, kq = i & 31;
        int gr = row0 + r;
        float4 v = (gr < n) ? *(const float4*)&x[gr * 128 + kq * 4] : make_float4(0, 0, 0, 0);
        *(float4*)&xs[r][kq * 4] = v;
    }
    __syncthreads();
    int rg = t / 20, cg = t % 20;
    int r0 = rg * 4, c0 = cg * 4;
    float4 acc0 = make_float4(0, 0, 0, 0), acc1 = acc0, acc2 = acc0, acc3 = acc0;
    for (int k = 0; k < 128; k += 4) {
        float4 w0 = *(float4*)&Ws[k + 0][c0];
        float4 w1 = *(float4*)&Ws[k + 1][c0];
        float4 w2 = *(float4*)&Ws[k + 2][c0];
        float4 w3 = *(float4*)&Ws[k + 3][c0];
#pragma unroll
        for (int j = 0; j < 4; ++j) {
            float4 xv = *(float4*)&xs[r0 + j][k];
            float4& a = j == 0 ? acc0 : j == 1 ? acc1 : j == 2 ? acc2 : acc3;
            a.x += xv.x * w0.x + xv.y * w1.x + xv.z * w2.x + xv.w * w3.x;
            a.y += xv.x * w0.y + xv.y * w1.y + xv.z * w2.y + xv.w * w3.y;
            a.z += xv.x * w0.z + xv.y * w1.z + xv.z * w2.z + xv.w * w3.z;
            a.w += xv.x * w0.w + xv.y * w1.w + xv.z * w2.w + xv.w * w3.w;
        }
    }
#pragma unroll
    for (int j = 0; j < 4; ++j) {
        int gr = row0 + r0 + j;
        if (gr >= n) break;
        float4 a = j == 0 ? acc0 : j == 1 ? acc1 : j == 2 ? acc2 : acc3;
        if (cg < 16) {
            unsigned p0 = ((unsigned)f2bf(a.y) << 16) | f2bf(a.x);
            unsigned p1 = ((unsigned)f2bf(a.w) << 16) | f2bf(a.z);
            *(uint2*)&h32[gr * 32 + (c0 >> 1)] = make_uint2(p0, p1);
        } else if (cg == 16) {
            *(float4*)&a1[gr * 4] = a;
        }
    }
}

// ---- bucketed CSR build: bucket = dst>>4 (16 nodes/bucket) ----
__global__ void bucket_count(const int* __restrict__ dstv, int E, int* __restrict__ bcnt) {
    int i = blockIdx.x * blockDim.x + threadIdx.x;
    if (i < E) atomicAdd(&bcnt[dstv[i] >> 4], 1);
}

// exclusive scan of nbuck (<=4096) bucket counts -> bstart[nbuck+1], bcur copy; also offs[n] = E
__global__ __launch_bounds__(1024) void scan_buckets(const int* __restrict__ bcnt, int nbuck,
                                                     int* __restrict__ bstart, int* __restrict__ bcur,
                                                     int* __restrict__ offs, int n, int E) {
    __shared__ int s[1024];
    int t = threadIdx.x;
    int v0[4];
    int lsum = 0;
#pragma unroll
    for (int j = 0; j < 4; ++j) {
        int i = t * 4 + j;
        v0[j] = (i < nbuck) ? bcnt[i] : 0;
        lsum += v0[j];
    }
    s[t] = lsum;
    __syncthreads();
    for (int o = 1; o < 1024; o <<= 1) {
        int u = (t >= o) ? s[t - o] : 0;
        __syncthreads();
        s[t] += u;
        __syncthreads();
    }
    int base = s[t] - lsum;
#pragma unroll
    for (int j = 0; j < 4; ++j) {
        int i = t * 4 + j;
        if (i < nbuck) { bstart[i] = base; bcur[i] = base; }
        base += v0[j];
    }
    if (t == 1023) { bstart[nbuck] = E; offs[n] = E; }
}

__global__ void bucket_scatter(const int* __restrict__ srcv, const int* __restrict__ dstv, int E,
                               int* __restrict__ bcur, int2* __restrict__ pairs) {
    int i = blockIdx.x * blockDim.x + threadIdx.x;
    if (i < E) {
        int d = dstv[i];
        int slot = atomicAdd(&bcur[d >> 4], 1);
        pairs[slot] = make_int2(srcv[i], d);
    }
}

// one block per bucket: LDS histogram over its 16 nodes -> offs + ordered srcs
__global__ __launch_bounds__(256) void build_csr(const int2* __restrict__ pairs,
                                                 const int* __restrict__ bstart, int n,
                                                 int* __restrict__ offs, int* __restrict__ srcs) {
    int b = blockIdx.x;
    int base = bstart[b], cnt = bstart[b + 1] - base;
    __shared__ int hist[16], curs[16];
    int t = threadIdx.x;
    if (t < 16) hist[t] = 0;
    __syncthreads();
    for (int i = t; i < cnt; i += 256) atomicAdd(&hist[pairs[base + i].y & 15], 1);
    __syncthreads();
    if (t == 0) {
        int s = 0;
#pragma unroll
        for (int j = 0; j < 16; ++j) { int h = hist[j]; hist[j] = s; curs[j] = s; s += h; }
    }
    __syncthreads();
    if (t < 16) {
        int node = b * 16 + t;
        if (node < n) offs[node] = base + hist[t];
    }
    for (int i = t; i < cnt; i += 256) {
        int2 p = pairs[base + i];
        int slot = atomicAdd(&curs[p.y & 15], 1);
        srcs[base + slot] = p.x;
    }
}

// layer-1 aggregation: one 64-lane wave per node; lanes 0..31 even edges, 32..63 odd; lane owns 2 channels
__global__ __launch_bounds__(256) void agg1(const unsigned* __restrict__ h32, const float* __restrict__ a1,
                                            const int* __restrict__ offs, const int* __restrict__ srcs,
                                            const float* __restrict__ b1, float* __restrict__ h1, int n) {
    int wid = threadIdx.x >> 6, lane = threadIdx.x & 63;
    int node = blockIdx.x * 4 + wid;
    if (node >= n) return;
    int half = lane >> 5;
    int l = lane & 31;
    int head = l >> 4;
    float adst = a1[node * 4 + 2 + head];
    float acc0 = 0.f, acc1 = 0.f, denom = 0.f;
    if (half == 0) {
        float w = __expf(lrelu(a1[node * 4 + head] + adst));
        unsigned hv = h32[node * 32 + l];
        acc0 = w * bf_lo(hv); acc1 = w * bf_hi(hv);
        denom = w;
    }
    int kb = offs[node], ke = offs[node + 1];
    for (int k = kb + half; k < ke; k += 2) {
        int s = srcs[k];
        float wv = __expf(lrelu(a1[s * 4 + head] + adst));
        unsigned hv = h32[s * 32 + l];
        denom += wv;
        acc0 += wv * bf_lo(hv);
        acc1 += wv * bf_hi(hv);
    }
    acc0  += __shfl(acc0,  lane ^ 32, 64);
    acc1  += __shfl(acc1,  lane ^ 32, 64);
    denom += __shfl(denom, lane ^ 32, 64);
    if (half == 0) {
        float o0 = acc0 / denom + b1[2 * l];
        float o1 = acc1 / denom + b1[2 * l + 1];
        *(float2*)&h1[node * 64 + 2 * l] = make_float2(fmaxf(o0, 0.f), fmaxf(o1, 0.f));
    }
}

// hml[N][16] = packed bf16x2 (lo=mu, hi=ls), a2[N][4] logit pieces
__global__ __launch_bounds__(256) void gemm2(const float* __restrict__ h1,
                                             const float* __restrict__ Wext,
                                             unsigned* __restrict__ hml, float* __restrict__ a2, int n) {
    __shared__ float hs[16][65];
    __shared__ float Ws[64][36];
    int t = threadIdx.x;
    int row0 = blockIdx.x * 16;
    for (int i = t; i < 64 * 36; i += 256) Ws[i / 36][i % 36] = Wext[i];
    for (int i = t; i < 16 * 64; i += 256) {
        int r = i >> 6, k = i & 63;
        int gr = row0 + r;
        hs[r][k] = (gr < n) ? h1[gr * 64 + k] : 0.f;
    }
    __syncthreads();
    int r = t >> 4, c = t & 15;
    float am = 0, al = 0;
    for (int k = 0; k < 64; ++k) {
        float hv = hs[r][k];
        am += hv * Ws[k][c];
        al += hv * Ws[k][16 + c];
    }
    int gr = row0 + r;
    if (gr < n) hml[gr * 16 + c] = ((unsigned)f2bf(al) << 16) | f2bf(am);
    if (t < 64) {
        int r2 = t >> 2, j = t & 3;
        float a = 0.f;
        for (int k = 0; k < 64; ++k) a += hs[r2][k] * Ws[k][32 + j];
        if (row0 + r2 < n) a2[(row0 + r2) * 4 + j] = a;
    }
}

// fused mu+ls aggregation: 32 lanes per node (two 16-lane halves over even/odd edges), 8 nodes/block
__global__ __launch_bounds__(256) void agg2(const unsigned* __restrict__ hml,
                                            const float* __restrict__ a2, const int* __restrict__ offs,
                                            const int* __restrict__ srcs,
                                            const float* __restrict__ bmu, const float* __restrict__ bls,
                                            float* __restrict__ out, int n) {
    int grp = threadIdx.x >> 5;
    int node = blockIdx.x * 8 + grp;
    if (node >= n) return;
    int lane32 = threadIdx.x & 31;
    int half = lane32 >> 4;
    int c = lane32 & 15;
    float admu = a2[node * 4 + 1], adls = a2[node * 4 + 3];
    float amu = 0.f, als = 0.f, dmu = 0.f, dls = 0.f;
    if (half == 0) {
        float wmu = __expf(lrelu(a2[node * 4 + 0] + admu));
        float wls = __expf(lrelu(a2[node * 4 + 2] + adls));
        unsigned hv = hml[node * 16 + c];
        amu = wmu * bf_lo(hv); als = wls * bf_hi(hv);
        dmu = wmu; dls = wls;
    }
    int kb = offs[node], ke = offs[node + 1];
    for (int k = kb + half; k < ke; k += 2) {
        int s = srcs[k];
        float4 av = *(const float4*)&a2[s * 4];
        float w1v = __expf(lrelu(av.x + admu));
        float w2v = __expf(lrelu(av.z + adls));
        unsigned hv = hml[s * 16 + c];
        dmu += w1v; dls += w2v;
        amu += w1v * bf_lo(hv);
        als += w2v * bf_hi(hv);
    }
    amu += __shfl_xor(amu, 16, 64);
    als += __shfl_xor(als, 16, 64);
    dmu += __shfl_xor(dmu, 16, 64);
    dls += __shfl_xor(dls, 16, 64);
    if (half == 0) {
        out[node * 16 + c] = amu / dmu + bmu[c];
        out[(size_t)n * 16 + node * 16 + c] = als / dls + bls[c];
    }
}

extern "C" void kernel_launch(void* const* d_in, const int* in_sizes, int n_in,
                              void* d_out, int out_size, void* d_ws, size_t ws_size,
                              hipStream_t stream) {
    const float* x    = (const float*)d_in[0];
    const int*   ei   = (const int*)d_in[1];
    const float* W1   = (const float*)d_in[2];
    const float* as1  = (const float*)d_in[3];
    const float* ad1  = (const float*)d_in[4];
    const float* b1   = (const float*)d_in[5];
    const float* Wmu  = (const float*)d_in[6];
    const float* asmu = (const float*)d_in[7];
    const float* admu = (const float*)d_in[8];
    const float* bmu  = (const float*)d_in[9];
    const float* Wls  = (const float*)d_in[10];
    const float* asls = (const float*)d_in[11];
    const float* adls = (const float*)d_in[12];
    const float* bls  = (const float*)d_in[13];
    float* out = (float*)d_out;

    int n = in_sizes[0] / 128;
    int E = in_sizes[1] / 2;
    int nbuck = (n + 15) >> 4;

    char* ws = (char*)d_ws;
    size_t off = 0;
    auto alloc = [&](size_t b) { size_t p = off; off = (off + b + 255) & ~(size_t)255; return p; };

    unsigned* h32 = (unsigned*)(ws + alloc((size_t)n * 32 * 4));
    float*    h1  = (float*)(ws + alloc((size_t)n * 64 * 4));
    float*    a1  = (float*)(ws + alloc((size_t)n * 4 * 4));
    unsigned* hml = (unsigned*)(ws + alloc((size_t)n * 16 * 4));
    float*    a2  = (float*)(ws + alloc((size_t)n * 4 * 4));
    float*    w1e = (float*)(ws + alloc(128 * 80 * 4));
    float*    w2e = (float*)(ws + alloc(64 * 36 * 4));
    int*   offs   = (int*)(ws + alloc((size_t)(n + 1) * 4));
    int*   srcs   = (int*)(ws + alloc((size_t)E * 4));
    int*   bcnt   = (int*)(ws + alloc((size_t)nbuck * 4));
    int*   bstart = (int*)(ws + alloc((size_t)(nbuck + 1) * 4));
    int*   bcur   = (int*)(ws + alloc((size_t)nbuck * 4));
    int2*  pairs  = (int2*)(ws + alloc((size_t)E * 8));

    hipMemsetAsync(bcnt, 0, (size_t)nbuck * 4, stream);
    build_w1ext<<<(128 * 80 + 255) / 256, 256, 0, stream>>>(W1, as1, ad1, w1e);
    build_w2ext<<<(64 * 36 + 255) / 256, 256, 0, stream>>>(Wmu, Wls, asmu, admu, asls, adls, w2e);
    gemm1<<<(n + 63) / 64, 320, 0, stream>>>(x, w1e, h32, a1, n);
    bucket_count<<<(E + 255) / 256, 256, 0, stream>>>(ei + E, E, bcnt);
    scan_buckets<<<1, 1024, 0, stream>>>(bcnt, nbuck, bstart, bcur, offs, n, E);
    bucket_scatter<<<(E + 255) / 256, 256, 0, stream>>>(ei, ei + E, E, bcur, pairs);
    build_csr<<<nbuck, 256, 0, stream>>>(pairs, bstart, n, offs, srcs);
    agg1<<<(n + 3) / 4, 256, 0, stream>>>(h32, a1, offs, srcs, b1, h1, n);
    gemm2<<<(n + 15) / 16, 256, 0, stream>>>(h1, w2e, hml, a2, n);
    agg2<<<(n + 7) / 8, 256, 0, stream>>>(hml, a2, offs, srcs, bmu, bls, out, n);
}

// Round 5
// 304.157 us; speedup vs baseline: 1.2771x; 1.2771x over previous
//
#include <hip/hip_runtime.h>

#define NEG 0.2f

__device__ __forceinline__ float lrelu(float v) { return v > 0.f ? v : NEG * v; }

__device__ __forceinline__ unsigned short f2bf(float f) {
    unsigned u = __float_as_uint(f);
    unsigned r = (u + 0x7FFF + ((u >> 16) & 1)) >> 16;   // RNE
    return (unsigned short)r;
}
__device__ __forceinline__ float bf_lo(unsigned v) { return __uint_as_float(v << 16); }
__device__ __forceinline__ float bf_hi(unsigned v) { return __uint_as_float(v & 0xffff0000u); }

// W1ext[128][80]: cols 0..63 = W1; col 64+j = W1[:, h*32:+32] @ att (j:0=src_h0,1=src_h1,2=dst_h0,3=dst_h1); 68..79 = 0
__global__ void build_w1ext(const float* __restrict__ W1, const float* __restrict__ asrc,
                            const float* __restrict__ adst, float* __restrict__ Wext) {
    int i = blockIdx.x * blockDim.x + threadIdx.x;
    if (i >= 128 * 80) return;
    int k = i / 80, c = i % 80;
    if (c < 64) { Wext[i] = W1[k * 64 + c]; return; }
    if (c >= 68) { Wext[i] = 0.f; return; }
    int j = c - 64;
    int hh = j & 1;
    const float* att = (j >= 2) ? adst : asrc;
    float s = 0.f;
    for (int d = 0; d < 32; ++d) s += W1[k * 64 + hh * 32 + d] * att[hh * 32 + d];
    Wext[i] = s;
}

// W2ext[64][36]: 0..15 = W_mu, 16..31 = W_ls, 32..35 = attention projection vectors
__global__ void build_w2ext(const float* __restrict__ Wmu, const float* __restrict__ Wls,
                            const float* __restrict__ asmu, const float* __restrict__ admu,
                            const float* __restrict__ asls, const float* __restrict__ adls,
                            float* __restrict__ Wext) {
    int i = blockIdx.x * blockDim.x + threadIdx.x;
    if (i >= 64 * 36) return;
    int k = i / 36, c = i % 36;
    if (c < 16) { Wext[i] = Wmu[k * 16 + c]; return; }
    if (c < 32) { Wext[i] = Wls[k * 16 + (c - 16)]; return; }
    int j = c - 32;
    const float* W = (j < 2) ? Wmu : Wls;
    const float* att = (j == 0) ? asmu : (j == 1) ? admu : (j == 2) ? asls : adls;
    float s = 0.f;
    for (int c2 = 0; c2 < 16; ++c2) s += W[k * 16 + c2] * att[c2];
    Wext[i] = s;
}

// h32[N][32] = packed bf16x2 of x @ W1, a1[N][4] f32. 64 rows/block, 4x4 register tile, float4 LDS reads.
__global__ __launch_bounds__(320) void gemm1(const float* __restrict__ x,
                                             const float* __restrict__ Wext,
                                             unsigned* __restrict__ h32, float* __restrict__ a1, int n) {
    __shared__ float xs[64][132];
    __shared__ float Ws[128][80];
    int t = threadIdx.x;
    int row0 = blockIdx.x * 64;
    for (int i = t; i < 128 * 20; i += 320) {
        int r = i / 20, cq = i % 20;
        *(float4*)&Ws[r][cq * 4] = *(const float4*)&Wext[r * 80 + cq * 4];
    }
    for (int i = t; i < 64 * 32; i += 320) {
        int r = i >> 5, kq = i & 31;
        int gr = row0 + r;
        float4 v = (gr < n) ? *(const float4*)&x[gr * 128 + kq * 4] : make_float4(0, 0, 0, 0);
        *(float4*)&xs[r][kq * 4] = v;
    }
    __syncthreads();
    int rg = t / 20, cg = t % 20;
    int r0 = rg * 4, c0 = cg * 4;
    float4 acc0 = make_float4(0, 0, 0, 0), acc1 = acc0, acc2 = acc0, acc3 = acc0;
    for (int k = 0; k < 128; k += 4) {
        float4 w0 = *(float4*)&Ws[k + 0][c0];
        float4 w1 = *(float4*)&Ws[k + 1][c0];
        float4 w2 = *(float4*)&Ws[k + 2][c0];
        float4 w3 = *(float4*)&Ws[k + 3][c0];
#pragma unroll
        for (int j = 0; j < 4; ++j) {
            float4 xv = *(float4*)&xs[r0 + j][k];
            float4& a = j == 0 ? acc0 : j == 1 ? acc1 : j == 2 ? acc2 : acc3;
            a.x += xv.x * w0.x + xv.y * w1.x + xv.z * w2.x + xv.w * w3.x;
            a.y += xv.x * w0.y + xv.y * w1.y + xv.z * w2.y + xv.w * w3.y;
            a.z += xv.x * w0.z + xv.y * w1.z + xv.z * w2.z + xv.w * w3.z;
            a.w += xv.x * w0.w + xv.y * w1.w + xv.z * w2.w + xv.w * w3.w;
        }
    }
#pragma unroll
    for (int j = 0; j < 4; ++j) {
        int gr = row0 + r0 + j;
        if (gr >= n) break;
        float4 a = j == 0 ? acc0 : j == 1 ? acc1 : j == 2 ? acc2 : acc3;
        if (cg < 16) {
            unsigned p0 = ((unsigned)f2bf(a.y) << 16) | f2bf(a.x);
            unsigned p1 = ((unsigned)f2bf(a.w) << 16) | f2bf(a.z);
            *(uint2*)&h32[gr * 32 + (c0 >> 1)] = make_uint2(p0, p1);
        } else if (cg == 16) {
            *(float4*)&a1[gr * 4] = a;
        }
    }
}

// ---- XCD-partitioned CSR build: partition p = blockIdx%8 owns nodes [p*np, p*np+np) ----
__global__ __launch_bounds__(256) void count_deg_part(const int* __restrict__ dstv, int E, int np,
                                                      int* __restrict__ deg) {
    int p = blockIdx.x & 7;
    int bslot = blockIdx.x >> 3;
    int nblk = gridDim.x >> 3;
    int lo = p * np, hi = lo + np;
    for (int i = bslot * 256 + threadIdx.x; i < E; i += nblk * 256) {
        int d = dstv[i];
        if (d >= lo && d < hi) atomicAdd(&deg[d], 1);
    }
}

__global__ __launch_bounds__(256) void scatter_part(const int* __restrict__ srcv,
                                                    const int* __restrict__ dstv, int E, int np,
                                                    int* __restrict__ cursor, int* __restrict__ srcs) {
    int p = blockIdx.x & 7;
    int bslot = blockIdx.x >> 3;
    int nblk = gridDim.x >> 3;
    int lo = p * np, hi = lo + np;
    for (int i = bslot * 256 + threadIdx.x; i < E; i += nblk * 256) {
        int d = dstv[i];
        if (d >= lo && d < hi) {
            int slot = atomicAdd(&cursor[d], 1);
            srcs[slot] = srcv[i];
        }
    }
}

// ---- 3-phase parallel scan of deg -> offs/cursor ----
__global__ __launch_bounds__(256) void block_sums(const int* __restrict__ deg, int n,
                                                  int* __restrict__ bsums) {
    int i = blockIdx.x * 256 + threadIdx.x;
    int v = (i < n) ? deg[i] : 0;
    for (int o = 32; o > 0; o >>= 1) v += __shfl_down(v, o, 64);
    __shared__ int ws[4];
    if ((threadIdx.x & 63) == 0) ws[threadIdx.x >> 6] = v;
    __syncthreads();
    if (threadIdx.x == 0) bsums[blockIdx.x] = ws[0] + ws[1] + ws[2] + ws[3];
}

__global__ __launch_bounds__(256) void scan_bsums(int* __restrict__ bsums, int nb) {
    __shared__ int s[256];
    int t = threadIdx.x;
    int v = (t < nb) ? bsums[t] : 0;
    s[t] = v;
    __syncthreads();
    for (int o = 1; o < 256; o <<= 1) {
        int u = (t >= o) ? s[t - o] : 0;
        __syncthreads();
        s[t] += u;
        __syncthreads();
    }
    if (t < nb) bsums[t] = s[t] - v;   // exclusive
}

__global__ __launch_bounds__(256) void write_offs(const int* __restrict__ deg,
                                                  const int* __restrict__ bsums, int n,
                                                  int* __restrict__ offs, int* __restrict__ cursor) {
    int t = threadIdx.x;
    int i = blockIdx.x * 256 + t;
    int v = (i < n) ? deg[i] : 0;
    __shared__ int s[256];
    s[t] = v;
    __syncthreads();
    for (int o = 1; o < 256; o <<= 1) {
        int u = (t >= o) ? s[t - o] : 0;
        __syncthreads();
        s[t] += u;
        __syncthreads();
    }
    int excl = s[t] - v + bsums[blockIdx.x];
    if (i < n) { offs[i] = excl; cursor[i] = excl; }
    if (i == n - 1) offs[n] = excl + v;
}

// layer-1 aggregation: one 64-lane wave per node; 4 edge phases (quarters), lane owns 4 channels (uint2)
__global__ __launch_bounds__(256) void agg1(const unsigned* __restrict__ h32, const float* __restrict__ a1,
                                            const int* __restrict__ offs, const int* __restrict__ srcs,
                                            const float* __restrict__ b1, float* __restrict__ h1, int n) {
    int wid = threadIdx.x >> 6, lane = threadIdx.x & 63;
    int node = blockIdx.x * 4 + wid;
    if (node >= n) return;
    int q = lane >> 4;          // edge phase 0..3
    int l = lane & 15;          // channels 4l..4l+3
    int head = l >> 3;
    float adst = a1[node * 4 + 2 + head];
    float ax = 0.f, ay = 0.f, az = 0.f, aw = 0.f, denom = 0.f;
    if (q == 0) {               // self loop
        float w = __expf(lrelu(a1[node * 4 + head] + adst));
        uint2 hv = *(const uint2*)&h32[node * 32 + 2 * l];
        ax = w * bf_lo(hv.x); ay = w * bf_hi(hv.x);
        az = w * bf_lo(hv.y); aw = w * bf_hi(hv.y);
        denom = w;
    }
    int kb = offs[node], ke = offs[node + 1];
    for (int k = kb + q; k < ke; k += 4) {
        int s = srcs[k];
        float wv = __expf(lrelu(a1[s * 4 + head] + adst));
        uint2 hv = *(const uint2*)&h32[s * 32 + 2 * l];
        denom += wv;
        ax += wv * bf_lo(hv.x); ay += wv * bf_hi(hv.x);
        az += wv * bf_lo(hv.y); aw += wv * bf_hi(hv.y);
    }
    ax += __shfl_xor(ax, 16, 64); ax += __shfl_xor(ax, 32, 64);
    ay += __shfl_xor(ay, 16, 64); ay += __shfl_xor(ay, 32, 64);
    az += __shfl_xor(az, 16, 64); az += __shfl_xor(az, 32, 64);
    aw += __shfl_xor(aw, 16, 64); aw += __shfl_xor(aw, 32, 64);
    denom += __shfl_xor(denom, 16, 64); denom += __shfl_xor(denom, 32, 64);
    if (q == 0) {
        float4 bv = *(const float4*)&b1[4 * l];
        float4 o;
        o.x = fmaxf(ax / denom + bv.x, 0.f);
        o.y = fmaxf(ay / denom + bv.y, 0.f);
        o.z = fmaxf(az / denom + bv.z, 0.f);
        o.w = fmaxf(aw / denom + bv.w, 0.f);
        *(float4*)&h1[node * 64 + 4 * l] = o;
    }
}

// hml[N][16] = packed bf16x2 (lo=mu, hi=ls), a2[N][4] logit pieces
__global__ __launch_bounds__(256) void gemm2(const float* __restrict__ h1,
                                             const float* __restrict__ Wext,
                                             unsigned* __restrict__ hml, float* __restrict__ a2, int n) {
    __shared__ float hs[16][65];
    __shared__ float Ws[64][36];
    int t = threadIdx.x;
    int row0 = blockIdx.x * 16;
    for (int i = t; i < 64 * 36; i += 256) Ws[i / 36][i % 36] = Wext[i];
    for (int i = t; i < 16 * 64; i += 256) {
        int r = i >> 6, k = i & 63;
        int gr = row0 + r;
        hs[r][k] = (gr < n) ? h1[gr * 64 + k] : 0.f;
    }
    __syncthreads();
    int r = t >> 4, c = t & 15;
    float am = 0, al = 0;
    for (int k = 0; k < 64; ++k) {
        float hv = hs[r][k];
        am += hv * Ws[k][c];
        al += hv * Ws[k][16 + c];
    }
    int gr = row0 + r;
    if (gr < n) hml[gr * 16 + c] = ((unsigned)f2bf(al) << 16) | f2bf(am);
    if (t < 64) {
        int r2 = t >> 2, j = t & 3;
        float a = 0.f;
        for (int k = 0; k < 64; ++k) a += hs[r2][k] * Ws[k][32 + j];
        if (row0 + r2 < n) a2[(row0 + r2) * 4 + j] = a;
    }
}

// fused mu+ls aggregation: one 64-lane wave per node; 4 edge phases, 16 lanes own channels
__global__ __launch_bounds__(256) void agg2(const unsigned* __restrict__ hml,
                                            const float* __restrict__ a2, const int* __restrict__ offs,
                                            const int* __restrict__ srcs,
                                            const float* __restrict__ bmu, const float* __restrict__ bls,
                                            float* __restrict__ out, int n) {
    int wid = threadIdx.x >> 6, lane = threadIdx.x & 63;
    int node = blockIdx.x * 4 + wid;
    if (node >= n) return;
    int q = lane >> 4, c = lane & 15;
    float admu = a2[node * 4 + 1], adls = a2[node * 4 + 3];
    float amu = 0.f, als = 0.f, dmu = 0.f, dls = 0.f;
    if (q == 0) {               // self loop
        float wmu = __expf(lrelu(a2[node * 4 + 0] + admu));
        float wls = __expf(lrelu(a2[node * 4 + 2] + adls));
        unsigned hv = hml[node * 16 + c];
        amu = wmu * bf_lo(hv); als = wls * bf_hi(hv);
        dmu = wmu; dls = wls;
    }
    int kb = offs[node], ke = offs[node + 1];
    for (int k = kb + q; k < ke; k += 4) {
        int s = srcs[k];
        float4 av = *(const float4*)&a2[s * 4];
        float w1v = __expf(lrelu(av.x + admu));
        float w2v = __expf(lrelu(av.z + adls));
        unsigned hv = hml[s * 16 + c];
        dmu += w1v; dls += w2v;
        amu += w1v * bf_lo(hv);
        als += w2v * bf_hi(hv);
    }
    amu += __shfl_xor(amu, 16, 64); amu += __shfl_xor(amu, 32, 64);
    als += __shfl_xor(als, 16, 64); als += __shfl_xor(als, 32, 64);
    dmu += __shfl_xor(dmu, 16, 64); dmu += __shfl_xor(dmu, 32, 64);
    dls += __shfl_xor(dls, 16, 64); dls += __shfl_xor(dls, 32, 64);
    if (q == 0) {
        out[node * 16 + c] = amu / dmu + bmu[c];
        out[(size_t)n * 16 + node * 16 + c] = als / dls + bls[c];
    }
}

extern "C" void kernel_launch(void* const* d_in, const int* in_sizes, int n_in,
                              void* d_out, int out_size, void* d_ws, size_t ws_size,
                              hipStream_t stream) {
    const float* x    = (const float*)d_in[0];
    const int*   ei   = (const int*)d_in[1];
    const float* W1   = (const float*)d_in[2];
    const float* as1  = (const float*)d_in[3];
    const float* ad1  = (const float*)d_in[4];
    const float* b1   = (const float*)d_in[5];
    const float* Wmu  = (const float*)d_in[6];
    const float* asmu = (const float*)d_in[7];
    const float* admu = (const float*)d_in[8];
    const float* bmu  = (const float*)d_in[9];
    const float* Wls  = (const float*)d_in[10];
    const float* asls = (const float*)d_in[11];
    const float* adls = (const float*)d_in[12];
    const float* bls  = (const float*)d_in[13];
    float* out = (float*)d_out;

    int n = in_sizes[0] / 128;
    int E = in_sizes[1] / 2;
    int np = (n + 7) / 8;       // nodes per XCD partition

    char* ws = (char*)d_ws;
    size_t off = 0;
    auto alloc = [&](size_t b) { size_t p = off; off = (off + b + 255) & ~(size_t)255; return p; };

    unsigned* h32 = (unsigned*)(ws + alloc((size_t)n * 32 * 4));
    float*    h1  = (float*)(ws + alloc((size_t)n * 64 * 4));
    float*    a1  = (float*)(ws + alloc((size_t)n * 4 * 4));
    unsigned* hml = (unsigned*)(ws + alloc((size_t)n * 16 * 4));
    float*    a2  = (float*)(ws + alloc((size_t)n * 4 * 4));
    float*    w1e = (float*)(ws + alloc(128 * 80 * 4));
    float*    w2e = (float*)(ws + alloc(64 * 36 * 4));
    int*   deg    = (int*)(ws + alloc((size_t)n * 4));
    int*   offs   = (int*)(ws + alloc((size_t)(n + 1) * 4));
    int*   cursor = (int*)(ws + alloc((size_t)n * 4));
    int*   srcs   = (int*)(ws + alloc((size_t)E * 4));
    int*   bsums  = (int*)(ws + alloc(1024 * 4));

    int nb = (n + 255) / 256;

    hipMemsetAsync(deg, 0, (size_t)n * 4, stream);
    build_w1ext<<<(128 * 80 + 255) / 256, 256, 0, stream>>>(W1, as1, ad1, w1e);
    build_w2ext<<<(64 * 36 + 255) / 256, 256, 0, stream>>>(Wmu, Wls, asmu, admu, asls, adls, w2e);
    gemm1<<<(n + 63) / 64, 320, 0, stream>>>(x, w1e, h32, a1, n);
    count_deg_part<<<2048, 256, 0, stream>>>(ei + E, E, np, deg);
    block_sums<<<nb, 256, 0, stream>>>(deg, n, bsums);
    scan_bsums<<<1, 256, 0, stream>>>(bsums, nb);
    write_offs<<<nb, 256, 0, stream>>>(deg, bsums, n, offs, cursor);
    scatter_part<<<2048, 256, 0, stream>>>(ei, ei + E, E, np, cursor, srcs);
    agg1<<<(n + 3) / 4, 256, 0, stream>>>(h32, a1, offs, srcs, b1, h1, n);
    gemm2<<<(n + 15) / 16, 256, 0, stream>>>(h1, w2e, hml, a2, n);
    agg2<<<(n + 3) / 4, 256, 0, stream>>>(hml, a2, offs, srcs, bmu, bls, out, n);
}

// Round 6
// 277.110 us; speedup vs baseline: 1.4017x; 1.0976x over previous
//
#include <hip/hip_runtime.h>

#define NEG 0.2f

typedef __attribute__((ext_vector_type(8))) short short8;
typedef __attribute__((ext_vector_type(4))) float f32x4;

__device__ __forceinline__ float lrelu(float v) { return v > 0.f ? v : NEG * v; }

__device__ __forceinline__ unsigned short f2bf(float f) {
    unsigned u = __float_as_uint(f);
    unsigned r = (u + 0x7FFF + ((u >> 16) & 1)) >> 16;   // RNE
    return (unsigned short)r;
}
__device__ __forceinline__ float bf2f(unsigned short h) { return __uint_as_float((unsigned)h << 16); }
__device__ __forceinline__ float bf_lo(unsigned v) { return __uint_as_float(v << 16); }
__device__ __forceinline__ float bf_hi(unsigned v) { return __uint_as_float(v & 0xffff0000u); }

// Wt1_{hi,lo}[80][128] bf16 transposed: col c, k. cols 0..63 = W1; 64+j = W1[:,h*32:+32]@att; 68..79 = 0
__global__ void build_w1ext(const float* __restrict__ W1, const float* __restrict__ asrc,
                            const float* __restrict__ adst,
                            unsigned short* __restrict__ Wt_hi, unsigned short* __restrict__ Wt_lo) {
    int i = blockIdx.x * blockDim.x + threadIdx.x;
    if (i >= 128 * 80) return;
    int k = i / 80, c = i % 80;
    float val;
    if (c < 64) val = W1[k * 64 + c];
    else if (c < 68) {
        int j = c - 64;
        int hh = j & 1;
        const float* att = (j >= 2) ? adst : asrc;
        float s = 0.f;
        for (int d = 0; d < 32; ++d) s += W1[k * 64 + hh * 32 + d] * att[hh * 32 + d];
        val = s;
    } else val = 0.f;
    unsigned short h = f2bf(val);
    Wt_hi[c * 128 + k] = h;
    Wt_lo[c * 128 + k] = f2bf(val - bf2f(h));
}

// Wt2_{hi,lo}[48][64] bf16 transposed: cols 0..15 = W_mu, 16..31 = W_ls, 32..35 = att proj, 36..47 = 0
__global__ void build_w2ext(const float* __restrict__ Wmu, const float* __restrict__ Wls,
                            const float* __restrict__ asmu, const float* __restrict__ admu,
                            const float* __restrict__ asls, const float* __restrict__ adls,
                            unsigned short* __restrict__ Wt_hi, unsigned short* __restrict__ Wt_lo) {
    int i = blockIdx.x * blockDim.x + threadIdx.x;
    if (i >= 64 * 48) return;
    int k = i / 48, c = i % 48;
    float val;
    if (c < 16) val = Wmu[k * 16 + c];
    else if (c < 32) val = Wls[k * 16 + (c - 16)];
    else if (c < 36) {
        int j = c - 32;
        const float* W = (j < 2) ? Wmu : Wls;
        const float* att = (j == 0) ? asmu : (j == 1) ? admu : (j == 2) ? asls : adls;
        float s = 0.f;
        for (int c2 = 0; c2 < 16; ++c2) s += W[k * 16 + c2] * att[c2];
        val = s;
    } else val = 0.f;
    unsigned short h = f2bf(val);
    Wt_hi[c * 64 + k] = h;
    Wt_lo[c * 64 + k] = f2bf(val - bf2f(h));
}

// MFMA gemm1: hbf[N][64] bf16 = x @ W1, a1[N][4] f32. 64 rows/block (4 waves x 16 rows), no LDS.
// hi/lo bf16 split on both operands (3 MFMAs), accuracy ~f32.
__global__ __launch_bounds__(256) void gemm1(const float* __restrict__ x,
                                             const unsigned short* __restrict__ Wt_hi,
                                             const unsigned short* __restrict__ Wt_lo,
                                             unsigned short* __restrict__ hbf,
                                             float* __restrict__ a1, int n) {
    int wid = threadIdx.x >> 6, lane = threadIdx.x & 63;
    int m = lane & 15, b = lane >> 4;
    int row = blockIdx.x * 64 + wid * 16 + m;
    int rowc = min(row, n - 1);
    short8 ah[4], al[4];
    const float* xp = x + (size_t)rowc * 128 + b * 8;
#pragma unroll
    for (int kc = 0; kc < 4; ++kc) {
        float4 v0 = *(const float4*)(xp + kc * 32);
        float4 v1 = *(const float4*)(xp + kc * 32 + 4);
        float vv[8] = {v0.x, v0.y, v0.z, v0.w, v1.x, v1.y, v1.z, v1.w};
#pragma unroll
        for (int j = 0; j < 8; ++j) {
            unsigned short h = f2bf(vv[j]);
            ah[kc][j] = (short)h;
            al[kc][j] = (short)f2bf(vv[j] - bf2f(h));
        }
    }
    int orow0 = blockIdx.x * 64 + wid * 16 + b * 4;
#pragma unroll
    for (int ct = 0; ct < 5; ++ct) {
        f32x4 acc = {0.f, 0.f, 0.f, 0.f};
        int col = ct * 16 + m;
        const unsigned short* wh = Wt_hi + col * 128 + b * 8;
        const unsigned short* wl = Wt_lo + col * 128 + b * 8;
#pragma unroll
        for (int kc = 0; kc < 4; ++kc) {
            short8 bh = *(const short8*)(wh + kc * 32);
            short8 bl = *(const short8*)(wl + kc * 32);
            acc = __builtin_amdgcn_mfma_f32_16x16x32_bf16(ah[kc], bh, acc, 0, 0, 0);
            acc = __builtin_amdgcn_mfma_f32_16x16x32_bf16(al[kc], bh, acc, 0, 0, 0);
            acc = __builtin_amdgcn_mfma_f32_16x16x32_bf16(ah[kc], bl, acc, 0, 0, 0);
        }
        if (ct < 4) {
#pragma unroll
            for (int j = 0; j < 4; ++j) {
                int orow = orow0 + j;
                if (orow < n) hbf[(size_t)orow * 64 + ct * 16 + m] = f2bf(acc[j]);
            }
        } else if (m < 4) {
#pragma unroll
            for (int j = 0; j < 4; ++j) {
                int orow = orow0 + j;
                if (orow < n) a1[(size_t)orow * 4 + m] = acc[j];
            }
        }
    }
}

// MFMA gemm2: hml[N][16] u32 (lo=mu,hi=ls) + a2[N][4] from h1bf[N][64] bf16. A single-bf16, B hi/lo.
__global__ __launch_bounds__(256) void gemm2(const unsigned short* __restrict__ h1bf,
                                             const unsigned short* __restrict__ Wt_hi,
                                             const unsigned short* __restrict__ Wt_lo,
                                             unsigned* __restrict__ hml, float* __restrict__ a2, int n) {
    int wid = threadIdx.x >> 6, lane = threadIdx.x & 63;
    int m = lane & 15, b = lane >> 4;
    int row = blockIdx.x * 64 + wid * 16 + m;
    int rowc = min(row, n - 1);
    short8 a0 = *(const short8*)(h1bf + (size_t)rowc * 64 + b * 8);
    short8 a1f = *(const short8*)(h1bf + (size_t)rowc * 64 + 32 + b * 8);
    int orow0 = blockIdx.x * 64 + wid * 16 + b * 4;
    f32x4 accs[3];
#pragma unroll
    for (int ct = 0; ct < 3; ++ct) {
        f32x4 acc = {0.f, 0.f, 0.f, 0.f};
        int col = ct * 16 + m;
        const unsigned short* wh = Wt_hi + col * 64 + b * 8;
        const unsigned short* wl = Wt_lo + col * 64 + b * 8;
        short8 bh0 = *(const short8*)(wh);
        short8 bl0 = *(const short8*)(wl);
        short8 bh1 = *(const short8*)(wh + 32);
        short8 bl1 = *(const short8*)(wl + 32);
        acc = __builtin_amdgcn_mfma_f32_16x16x32_bf16(a0, bh0, acc, 0, 0, 0);
        acc = __builtin_amdgcn_mfma_f32_16x16x32_bf16(a0, bl0, acc, 0, 0, 0);
        acc = __builtin_amdgcn_mfma_f32_16x16x32_bf16(a1f, bh1, acc, 0, 0, 0);
        acc = __builtin_amdgcn_mfma_f32_16x16x32_bf16(a1f, bl1, acc, 0, 0, 0);
        accs[ct] = acc;
    }
#pragma unroll
    for (int j = 0; j < 4; ++j) {
        int orow = orow0 + j;
        if (orow >= n) break;
        hml[(size_t)orow * 16 + m] = ((unsigned)f2bf(accs[1][j]) << 16) | f2bf(accs[0][j]);
        if (m < 4) a2[(size_t)orow * 4 + m] = accs[2][j];
    }
}

// ---- XCD-partitioned CSR build ----
__global__ __launch_bounds__(256) void count_deg_part(const int* __restrict__ dstv, int E, int np,
                                                      int* __restrict__ deg) {
    int p = blockIdx.x & 7;
    int bslot = blockIdx.x >> 3;
    int nblk = gridDim.x >> 3;
    int lo = p * np, hi = lo + np;
    for (int i = bslot * 256 + threadIdx.x; i < E; i += nblk * 256) {
        int d = dstv[i];
        if (d >= lo && d < hi) atomicAdd(&deg[d], 1);
    }
}

__global__ __launch_bounds__(256) void scatter_part(const int* __restrict__ srcv,
                                                    const int* __restrict__ dstv, int E, int np,
                                                    int* __restrict__ cursor, int* __restrict__ srcs) {
    int p = blockIdx.x & 7;
    int bslot = blockIdx.x >> 3;
    int nblk = gridDim.x >> 3;
    int lo = p * np, hi = lo + np;
    for (int i = bslot * 256 + threadIdx.x; i < E; i += nblk * 256) {
        int d = dstv[i];
        if (d >= lo && d < hi) {
            int slot = atomicAdd(&cursor[d], 1);
            srcs[slot] = srcv[i];
        }
    }
}

// ---- 3-phase parallel scan of deg -> offs/cursor ----
__global__ __launch_bounds__(256) void block_sums(const int* __restrict__ deg, int n,
                                                  int* __restrict__ bsums) {
    int i = blockIdx.x * 256 + threadIdx.x;
    int v = (i < n) ? deg[i] : 0;
    for (int o = 32; o > 0; o >>= 1) v += __shfl_down(v, o, 64);
    __shared__ int ws[4];
    if ((threadIdx.x & 63) == 0) ws[threadIdx.x >> 6] = v;
    __syncthreads();
    if (threadIdx.x == 0) bsums[blockIdx.x] = ws[0] + ws[1] + ws[2] + ws[3];
}

__global__ __launch_bounds__(256) void scan_bsums(int* __restrict__ bsums, int nb) {
    __shared__ int s[256];
    int t = threadIdx.x;
    int v = (t < nb) ? bsums[t] : 0;
    s[t] = v;
    __syncthreads();
    for (int o = 1; o < 256; o <<= 1) {
        int u = (t >= o) ? s[t - o] : 0;
        __syncthreads();
        s[t] += u;
        __syncthreads();
    }
    if (t < nb) bsums[t] = s[t] - v;   // exclusive
}

__global__ __launch_bounds__(256) void write_offs(const int* __restrict__ deg,
                                                  const int* __restrict__ bsums, int n,
                                                  int* __restrict__ offs, int* __restrict__ cursor) {
    int t = threadIdx.x;
    int i = blockIdx.x * 256 + t;
    int v = (i < n) ? deg[i] : 0;
    __shared__ int s[256];
    s[t] = v;
    __syncthreads();
    for (int o = 1; o < 256; o <<= 1) {
        int u = (t >= o) ? s[t - o] : 0;
        __syncthreads();
        s[t] += u;
        __syncthreads();
    }
    int excl = s[t] - v + bsums[blockIdx.x];
    if (i < n) { offs[i] = excl; cursor[i] = excl; }
    if (i == n - 1) offs[n] = excl + v;
}

// layer-1 aggregation: one 64-lane wave per node; 4 edge phases, lane owns 4 channels; bf16 output
__global__ __launch_bounds__(256) void agg1(const unsigned* __restrict__ h32, const float* __restrict__ a1,
                                            const int* __restrict__ offs, const int* __restrict__ srcs,
                                            const float* __restrict__ b1, unsigned* __restrict__ h1u, int n) {
    int wid = threadIdx.x >> 6, lane = threadIdx.x & 63;
    int node = blockIdx.x * 4 + wid;
    if (node >= n) return;
    int q = lane >> 4;          // edge phase 0..3
    int l = lane & 15;          // channels 4l..4l+3
    int head = l >> 3;
    float adst = a1[node * 4 + 2 + head];
    float ax = 0.f, ay = 0.f, az = 0.f, aw = 0.f, denom = 0.f;
    if (q == 0) {               // self loop
        float w = __expf(lrelu(a1[node * 4 + head] + adst));
        uint2 hv = *(const uint2*)&h32[node * 32 + 2 * l];
        ax = w * bf_lo(hv.x); ay = w * bf_hi(hv.x);
        az = w * bf_lo(hv.y); aw = w * bf_hi(hv.y);
        denom = w;
    }
    int kb = offs[node], ke = offs[node + 1];
    for (int k = kb + q; k < ke; k += 4) {
        int s = srcs[k];
        float wv = __expf(lrelu(a1[s * 4 + head] + adst));
        uint2 hv = *(const uint2*)&h32[s * 32 + 2 * l];
        denom += wv;
        ax += wv * bf_lo(hv.x); ay += wv * bf_hi(hv.x);
        az += wv * bf_lo(hv.y); aw += wv * bf_hi(hv.y);
    }
    ax += __shfl_xor(ax, 16, 64); ax += __shfl_xor(ax, 32, 64);
    ay += __shfl_xor(ay, 16, 64); ay += __shfl_xor(ay, 32, 64);
    az += __shfl_xor(az, 16, 64); az += __shfl_xor(az, 32, 64);
    aw += __shfl_xor(aw, 16, 64); aw += __shfl_xor(aw, 32, 64);
    denom += __shfl_xor(denom, 16, 64); denom += __shfl_xor(denom, 32, 64);
    if (q == 0) {
        float4 bv = *(const float4*)&b1[4 * l];
        float o0 = fmaxf(ax / denom + bv.x, 0.f);
        float o1 = fmaxf(ay / denom + bv.y, 0.f);
        float o2 = fmaxf(az / denom + bv.z, 0.f);
        float o3 = fmaxf(aw / denom + bv.w, 0.f);
        uint2 o;
        o.x = ((unsigned)f2bf(o1) << 16) | f2bf(o0);
        o.y = ((unsigned)f2bf(o3) << 16) | f2bf(o2);
        *(uint2*)&h1u[node * 32 + 2 * l] = o;
    }
}

// fused mu+ls aggregation: one 64-lane wave per node; 4 edge phases, 16 lanes own channels
__global__ __launch_bounds__(256) void agg2(const unsigned* __restrict__ hml,
                                            const float* __restrict__ a2, const int* __restrict__ offs,
                                            const int* __restrict__ srcs,
                                            const float* __restrict__ bmu, const float* __restrict__ bls,
                                            float* __restrict__ out, int n) {
    int wid = threadIdx.x >> 6, lane = threadIdx.x & 63;
    int node = blockIdx.x * 4 + wid;
    if (node >= n) return;
    int q = lane >> 4, c = lane & 15;
    float admu = a2[node * 4 + 1], adls = a2[node * 4 + 3];
    float amu = 0.f, als = 0.f, dmu = 0.f, dls = 0.f;
    if (q == 0) {               // self loop
        float wmu = __expf(lrelu(a2[node * 4 + 0] + admu));
        float wls = __expf(lrelu(a2[node * 4 + 2] + adls));
        unsigned hv = hml[node * 16 + c];
        amu = wmu * bf_lo(hv); als = wls * bf_hi(hv);
        dmu = wmu; dls = wls;
    }
    int kb = offs[node], ke = offs[node + 1];
    for (int k = kb + q; k < ke; k += 4) {
        int s = srcs[k];
        float4 av = *(const float4*)&a2[s * 4];
        float w1v = __expf(lrelu(av.x + admu));
        float w2v = __expf(lrelu(av.z + adls));
        unsigned hv = hml[s * 16 + c];
        dmu += w1v; dls += w2v;
        amu += w1v * bf_lo(hv);
        als += w2v * bf_hi(hv);
    }
    amu += __shfl_xor(amu, 16, 64); amu += __shfl_xor(amu, 32, 64);
    als += __shfl_xor(als, 16, 64); als += __shfl_xor(als, 32, 64);
    dmu += __shfl_xor(dmu, 16, 64); dmu += __shfl_xor(dmu, 32, 64);
    dls += __shfl_xor(dls, 16, 64); dls += __shfl_xor(dls, 32, 64);
    if (q == 0) {
        out[node * 16 + c] = amu / dmu + bmu[c];
        out[(size_t)n * 16 + node * 16 + c] = als / dls + bls[c];
    }
}

extern "C" void kernel_launch(void* const* d_in, const int* in_sizes, int n_in,
                              void* d_out, int out_size, void* d_ws, size_t ws_size,
                              hipStream_t stream) {
    const float* x    = (const float*)d_in[0];
    const int*   ei   = (const int*)d_in[1];
    const float* W1   = (const float*)d_in[2];
    const float* as1  = (const float*)d_in[3];
    const float* ad1  = (const float*)d_in[4];
    const float* b1   = (const float*)d_in[5];
    const float* Wmu  = (const float*)d_in[6];
    const float* asmu = (const float*)d_in[7];
    const float* admu = (const float*)d_in[8];
    const float* bmu  = (const float*)d_in[9];
    const float* Wls  = (const float*)d_in[10];
    const float* asls = (const float*)d_in[11];
    const float* adls = (const float*)d_in[12];
    const float* bls  = (const float*)d_in[13];
    float* out = (float*)d_out;

    int n = in_sizes[0] / 128;
    int E = in_sizes[1] / 2;
    int np = (n + 7) / 8;       // nodes per XCD partition

    char* ws = (char*)d_ws;
    size_t off = 0;
    auto alloc = [&](size_t b) { size_t p = off; off = (off + b + 255) & ~(size_t)255; return p; };

    unsigned short* hbf  = (unsigned short*)(ws + alloc((size_t)n * 64 * 2));
    unsigned*       h1u  = (unsigned*)(ws + alloc((size_t)n * 32 * 4));
    float*          a1   = (float*)(ws + alloc((size_t)n * 4 * 4));
    unsigned*       hml  = (unsigned*)(ws + alloc((size_t)n * 16 * 4));
    float*          a2   = (float*)(ws + alloc((size_t)n * 4 * 4));
    unsigned short* w1h  = (unsigned short*)(ws + alloc(80 * 128 * 2));
    unsigned short* w1l  = (unsigned short*)(ws + alloc(80 * 128 * 2));
    unsigned short* w2h  = (unsigned short*)(ws + alloc(48 * 64 * 2));
    unsigned short* w2l  = (unsigned short*)(ws + alloc(48 * 64 * 2));
    int*   deg    = (int*)(ws + alloc((size_t)n * 4));
    int*   offs   = (int*)(ws + alloc((size_t)(n + 1) * 4));
    int*   cursor = (int*)(ws + alloc((size_t)n * 4));
    int*   srcs   = (int*)(ws + alloc((size_t)E * 4));
    int*   bsums  = (int*)(ws + alloc(1024 * 4));

    int nb = (n + 255) / 256;

    hipMemsetAsync(deg, 0, (size_t)n * 4, stream);
    build_w1ext<<<(128 * 80 + 255) / 256, 256, 0, stream>>>(W1, as1, ad1, w1h, w1l);
    build_w2ext<<<(64 * 48 + 255) / 256, 256, 0, stream>>>(Wmu, Wls, asmu, admu, asls, adls, w2h, w2l);
    gemm1<<<(n + 63) / 64, 256, 0, stream>>>(x, w1h, w1l, hbf, a1, n);
    count_deg_part<<<2048, 256, 0, stream>>>(ei + E, E, np, deg);
    block_sums<<<nb, 256, 0, stream>>>(deg, n, bsums);
    scan_bsums<<<1, 256, 0, stream>>>(bsums, nb);
    write_offs<<<nb, 256, 0, stream>>>(deg, bsums, n, offs, cursor);
    scatter_part<<<2048, 256, 0, stream>>>(ei, ei + E, E, np, cursor, srcs);
    agg1<<<(n + 3) / 4, 256, 0, stream>>>((const unsigned*)hbf, a1, offs, srcs, b1, h1u, n);
    gemm2<<<(n + 63) / 64, 256, 0, stream>>>((const unsigned short*)h1u, w2h, w2l, hml, a2, n);
    agg2<<<(n + 3) / 4, 256, 0, stream>>>(hml, a2, offs, srcs, bmu, bls, out, n);
}